// Round 10
// baseline (82.747 us; speedup 1.0000x reference)
//
#include <hip/hip_runtime.h>
#include <utility>

// reference == inverse(M M^T + EPS*I) per pixel, M = x[b,:,:,h,w]^T (16x64)
// x: [B=4, C=64, K=16, H=128, W=128] f32 ; out: [B,H,W,16,16] f32
// Fused, 64 px/block, 128 threads (2 waves), NO LDS staging:
//   phase 1: gram from DIRECT coalesced global loads (lane = pixel, b32,
//            lane-consecutive -> 256B/instr). Wave w computes pairs
//            [68w,68w+68) -> acc[68]. Zero barriers, no LDS pipe use,
//            latency hidden by 16+ independent loads x 8 waves/CU.
//   phase 2: acc -> LDS tri[136][67] (+EPS diag)
//   phase 3: wave 0, lane = pixel: tri -> REGISTER Cholesky -> L^-1 -> M^T M -> tri
//   phase 4: 128 threads gather-store coalesced (each thread 2 elements)
// LDS: tri 36.4KB only -> 4 blocks/CU, 2 waves/SIMD -> VGPR cap 256.

#define EPSR 1e-6f

__device__ __host__ constexpr int rowof(int t) {
    int i = 0;
    while ((i + 1) * (i + 2) / 2 <= t) ++i;
    return i;
}
__device__ __host__ constexpr int colof(int t) { return t - rowof(t) * (rowof(t) + 1) / 2; }

__device__ __forceinline__ constexpr int tidx(int i, int j) {  // i >= j
    return i * (i + 1) / 2 + j;
}

// ---------------- pair-split template machinery (68/wave) ----------------

template<int P>
__device__ __forceinline__ void fma_pair(const float (&m)[16], float& a) {
    a = fmaf(m[rowof(P)], m[colof(P)], a);
}

template<int G, int... TT>
__device__ __forceinline__ void fma_group(const float (&m)[16], float (&acc)[68],
                                          std::integer_sequence<int, TT...>) {
    (fma_pair<G * 68 + TT>(m, acc[TT]), ...);
}

template<int G>
__device__ __forceinline__ void gram_direct(const float* __restrict__ xb,
                                            float (&acc)[68]) {
    #pragma unroll 2
    for (int c = 0; c < 64; ++c) {
        float m[16];
        #pragma unroll
        for (int k = 0; k < 16; ++k)
            m[k] = xb[(size_t)c * 262144 + (size_t)k * 16384];
        fma_group<G>(m, acc, std::make_integer_sequence<int, 68>{});
    }
}

template<int P>
__device__ __forceinline__ void store_tri_pair(float* __restrict__ tri, int lane, float v) {
    constexpr bool diag = (rowof(P) == colof(P));
    tri[P * 67 + lane] = diag ? (v + EPSR) : v;
}

template<int G, int... TT>
__device__ __forceinline__ void store_tri_group(float* __restrict__ tri, int lane,
                                                const float (&acc)[68],
                                                std::integer_sequence<int, TT...>) {
    (store_tri_pair<G * 68 + TT>(tri, lane, acc[TT]), ...);
}

// ---------------- fused kernel ----------------

__global__ __launch_bounds__(128, 2)
void fused_gram_inv(const float* __restrict__ x, float* __restrict__ out) {
    __shared__ float tri[136 * 67];           // 36.4 KB; row = pair, col = pixel

    const int tid = threadIdx.x;
    const int lane = tid & 63;
    const int wv = tid >> 6;                  // 0 or 1
    const int p0 = blockIdx.x * 64;
    const int b = blockIdx.x >> 8;
    const int hw0 = p0 & 16383;

    // lane = pixel: per-lane base, lane-consecutive 4B -> fully coalesced b32
    const float* xb = x + (size_t)b * 16777216 + hw0 + lane;

    float acc[68];
    #pragma unroll
    for (int t = 0; t < 68; ++t) acc[t] = 0.0f;

    // ---- phase 1: direct-load gram, no barriers ----
    if (wv == 0) gram_direct<0>(xb, acc);
    else         gram_direct<1>(xb, acc);

    // ---- phase 2: acc -> tri (+EPS on diag); waves write disjoint rows ----
    if (wv == 0) store_tri_group<0>(tri, lane, acc, std::make_integer_sequence<int, 68>{});
    else         store_tri_group<1>(tri, lane, acc, std::make_integer_sequence<int, 68>{});
    __syncthreads();

    // ---- phase 3: wave 0, lane = pixel, REGISTER inversion ----
    if (wv == 0) {
        float s[136];
        #pragma unroll
        for (int t = 0; t < 136; ++t) s[t] = tri[t * 67 + lane];

        // Cholesky in place: off-diag = L[i][j], diag = 1/L[j][j]
        #pragma unroll
        for (int j = 0; j < 16; ++j) {
            float d = s[tidx(j, j)];
            #pragma unroll
            for (int q = 0; q < j; ++q) d = fmaf(-s[tidx(j, q)], s[tidx(j, q)], d);
            const float invd = 1.0f / sqrtf(d);
            s[tidx(j, j)] = invd;
            #pragma unroll
            for (int i = j + 1; i < 16; ++i) {
                float v = s[tidx(i, j)];
                #pragma unroll
                for (int q = 0; q < j; ++q) v = fmaf(-s[tidx(i, q)], s[tidx(j, q)], v);
                s[tidx(i, j)] = v * invd;
            }
        }

        // M = L^{-1} in place (diag already inverted)
        #pragma unroll
        for (int j = 0; j < 16; ++j) {
            #pragma unroll
            for (int i = j + 1; i < 16; ++i) {
                float sum = s[tidx(i, j)] * s[tidx(j, j)];
                #pragma unroll
                for (int q = j + 1; q < i; ++q)
                    sum = fmaf(s[tidx(i, q)], s[tidx(q, j)], sum);
                s[tidx(i, j)] = -s[tidx(i, i)] * sum;
            }
        }

        // A^{-1} = M^T M in place
        #pragma unroll
        for (int j = 0; j < 16; ++j) {
            #pragma unroll
            for (int i = j; i < 16; ++i) {
                float sum = 0.0f;
                #pragma unroll
                for (int q = i; q < 16; ++q)
                    sum = fmaf(s[tidx(q, i)], s[tidx(q, j)], sum);
                s[tidx(i, j)] = sum;
            }
        }

        // writeback
        #pragma unroll
        for (int t = 0; t < 136; ++t) tri[t * 67 + lane] = s[t];
    }
    __syncthreads();

    // ---- phase 4: gather-store, each thread handles elements tid and tid+128 ----
    const int e0 = tid;                 // 0..127
    const int e1 = tid + 128;           // 128..255
    const int i0 = e0 >> 4, j0 = e0 & 15;
    const int h0 = i0 > j0 ? i0 : j0, l0 = i0 + j0 - h0;
    const int trow0 = h0 * (h0 + 1) / 2 + l0;
    const int i1 = e1 >> 4, j1 = e1 & 15;
    const int h1 = i1 > j1 ? i1 : j1, l1 = i1 + j1 - h1;
    const int trow1 = h1 * (h1 + 1) / 2 + l1;

    float* gout = out + (size_t)p0 * 256;
    #pragma unroll 8
    for (int a = 0; a < 64; ++a) {
        gout[(size_t)a * 256 + e0] = tri[trow0 * 67 + a];
        gout[(size_t)a * 256 + e1] = tri[trow1 * 67 + a];
    }
}

extern "C" void kernel_launch(void* const* d_in, const int* in_sizes, int n_in,
                              void* d_out, int out_size, void* d_ws, size_t ws_size,
                              hipStream_t stream) {
    const float* x = (const float*)d_in[0];
    float* out = (float*)d_out;
    hipLaunchKernelGGL(fused_gram_inv, dim3(1024), dim3(128), 0, stream, x, out);
}

// Round 11
// 78.285 us; speedup vs baseline: 1.0570x; 1.0570x over previous
//
#include <hip/hip_runtime.h>
#include <utility>

// reference == inverse(M M^T + EPS*I) per pixel, M = x[b,:,:,h,w]^T (16x64)
// x: [B=4, C=64, K=16, H=128, W=128] f32 ; out: [B,H,W,16,16] f32
// Fused, 64 px/block, 128 threads (2 waves):
//   phase 1: gram via global_load_lds, 4-buffer x 8KB chunks (2 c's each),
//            COUNTED vmcnt(8) waits -> 3 chunks in flight across barriers,
//            LDS stage (32KB) unions with tri (36.4KB) -> 4 blocks/CU kept.
//   phase 2: acc -> LDS tri[136][67] (+EPS diag)
//   phase 3: wave 0, lane = pixel: tri -> REGISTER Cholesky -> L^-1 -> M^T M -> tri
//   phase 4: 128 threads gather-store coalesced (each thread 2 elements)

#define EPSR 1e-6f

__device__ __host__ constexpr int rowof(int t) {
    int i = 0;
    while ((i + 1) * (i + 2) / 2 <= t) ++i;
    return i;
}
__device__ __host__ constexpr int colof(int t) { return t - rowof(t) * (rowof(t) + 1) / 2; }

__device__ __forceinline__ constexpr int tidx(int i, int j) {  // i >= j
    return i * (i + 1) / 2 + j;
}

#define GLOAD_LDS16(gp, lp)                                                       \
    __builtin_amdgcn_global_load_lds(                                             \
        (const __attribute__((address_space(1))) void*)(gp),                      \
        (__attribute__((address_space(3))) void*)(lp), 16, 0, 0)

// ---------------- pair-split template machinery (68/wave) ----------------

template<int P>
__device__ __forceinline__ void fma_pair(const float (&m)[16], float& a) {
    a = fmaf(m[rowof(P)], m[colof(P)], a);
}

template<int G, int... TT>
__device__ __forceinline__ void fma_group(const float (&m)[16], float (&acc)[68],
                                          std::integer_sequence<int, TT...>) {
    (fma_pair<G * 68 + TT>(m, acc[TT]), ...);
}

template<int G>
__device__ __forceinline__ void chunk_fma2(const float* __restrict__ buf, int lane,
                                           float (&acc)[68]) {
    #pragma unroll
    for (int cs = 0; cs < 2; ++cs) {
        float m[16];
        #pragma unroll
        for (int k = 0; k < 16; ++k) m[k] = buf[cs * 1024 + k * 64 + lane];
        fma_group<G>(m, acc, std::make_integer_sequence<int, 68>{});
    }
}

template<int P>
__device__ __forceinline__ void store_tri_pair(float* __restrict__ tri, int lane, float v) {
    constexpr bool diag = (rowof(P) == colof(P));
    tri[P * 67 + lane] = diag ? (v + EPSR) : v;
}

template<int G, int... TT>
__device__ __forceinline__ void store_tri_group(float* __restrict__ tri, int lane,
                                                const float (&acc)[68],
                                                std::integer_sequence<int, TT...>) {
    (store_tri_pair<G * 68 + TT>(tri, lane, acc[TT]), ...);
}

// ---------------- fused kernel ----------------

union SMem {
    float stage[4][2048];      // 4 x 8 KB chunks: [cs(0..1)*1024 + k*64 + px]
    float tri[136 * 67];       // 36.4 KB; row = pair index, col = pixel
};

__global__ __launch_bounds__(128, 2)
void fused_gram_inv(const float* __restrict__ x, float* __restrict__ out) {
    __shared__ __align__(16) SMem sm;

    const int tid = threadIdx.x;
    const int lane = tid & 63;
    const int wv = tid >> 6;                  // 0 or 1
    const int p0 = blockIdx.x * 64;
    const int b = blockIdx.x >> 8;
    const int hw0 = p0 & 16383;

    // staging src: lane l covers k-row (l>>4), px (l&15)*4..+3  (16B/lane)
    const float* gbase = x + (size_t)b * 16777216 + hw0
                           + (size_t)(lane >> 4) * 16384 + (size_t)(lane & 15) * 4;

    float acc[68];
    #pragma unroll
    for (int t = 0; t < 68; ++t) acc[t] = 0.0f;

    // chunk t covers channels {2t, 2t+1}; wave wv stages c = 2t+wv (4 instrs)
    auto STAGE = [&](int bufi, int t) {
        const float* gp = gbase + (size_t)(2 * t + wv) * 262144;
        #pragma unroll
        for (int q = 0; q < 4; ++q) {
            GLOAD_LDS16(gp + (size_t)(q * 4) * 16384,
                        &sm.stage[bufi][(wv * 16 + q * 4) * 64]);
        }
    };

    // ---- phase 1: 4-buffer counted-vmcnt pipeline, 32 chunks ----
    STAGE(0, 0);
    STAGE(1, 1);
    STAGE(2, 2);                               // 12 loads outstanding / wave
    for (int t = 0; t < 30; ++t) {
        // wait until chunk t landed; chunks t+1,t+2 (8 loads) stay in flight
        asm volatile("s_waitcnt vmcnt(8)" ::: "memory");
        __builtin_amdgcn_s_barrier();
        if (t < 29) STAGE((t + 3) & 3, t + 3);
        const float* buf = sm.stage[t & 3];
        if (wv == 0) chunk_fma2<0>(buf, lane, acc);
        else         chunk_fma2<1>(buf, lane, acc);
    }
    {   // t = 30: only chunk 31 (4 loads) may remain in flight
        asm volatile("s_waitcnt vmcnt(4)" ::: "memory");
        __builtin_amdgcn_s_barrier();
        const float* buf = sm.stage[30 & 3];
        if (wv == 0) chunk_fma2<0>(buf, lane, acc);
        else         chunk_fma2<1>(buf, lane, acc);
    }
    {   // t = 31: full drain
        asm volatile("s_waitcnt vmcnt(0)" ::: "memory");
        __builtin_amdgcn_s_barrier();
        const float* buf = sm.stage[31 & 3];
        if (wv == 0) chunk_fma2<0>(buf, lane, acc);
        else         chunk_fma2<1>(buf, lane, acc);
    }
    __syncthreads();   // all stage reads done before aliasing stage as tri

    // ---- phase 2: acc -> tri (+EPS on diag); waves write disjoint rows ----
    if (wv == 0) store_tri_group<0>(sm.tri, lane, acc, std::make_integer_sequence<int, 68>{});
    else         store_tri_group<1>(sm.tri, lane, acc, std::make_integer_sequence<int, 68>{});
    __syncthreads();

    // ---- phase 3: wave 0, lane = pixel, REGISTER inversion ----
    if (wv == 0) {
        float s[136];
        #pragma unroll
        for (int t = 0; t < 136; ++t) s[t] = sm.tri[t * 67 + lane];

        // Cholesky in place: off-diag = L[i][j], diag = 1/L[j][j]
        #pragma unroll
        for (int j = 0; j < 16; ++j) {
            float d = s[tidx(j, j)];
            #pragma unroll
            for (int q = 0; q < j; ++q) d = fmaf(-s[tidx(j, q)], s[tidx(j, q)], d);
            const float invd = 1.0f / sqrtf(d);
            s[tidx(j, j)] = invd;
            #pragma unroll
            for (int i = j + 1; i < 16; ++i) {
                float v = s[tidx(i, j)];
                #pragma unroll
                for (int q = 0; q < j; ++q) v = fmaf(-s[tidx(i, q)], s[tidx(j, q)], v);
                s[tidx(i, j)] = v * invd;
            }
        }

        // M = L^{-1} in place (diag already inverted)
        #pragma unroll
        for (int j = 0; j < 16; ++j) {
            #pragma unroll
            for (int i = j + 1; i < 16; ++i) {
                float sum = s[tidx(i, j)] * s[tidx(j, j)];
                #pragma unroll
                for (int q = j + 1; q < i; ++q)
                    sum = fmaf(s[tidx(i, q)], s[tidx(q, j)], sum);
                s[tidx(i, j)] = -s[tidx(i, i)] * sum;
            }
        }

        // A^{-1} = M^T M in place
        #pragma unroll
        for (int j = 0; j < 16; ++j) {
            #pragma unroll
            for (int i = j; i < 16; ++i) {
                float sum = 0.0f;
                #pragma unroll
                for (int q = i; q < 16; ++q)
                    sum = fmaf(s[tidx(q, i)], s[tidx(q, j)], sum);
                s[tidx(i, j)] = sum;
            }
        }

        // writeback
        #pragma unroll
        for (int t = 0; t < 136; ++t) sm.tri[t * 67 + lane] = s[t];
    }
    __syncthreads();

    // ---- phase 4: gather-store, each thread handles elements tid and tid+128 ----
    const int e0 = tid;                 // 0..127
    const int e1 = tid + 128;           // 128..255
    const int i0 = e0 >> 4, j0 = e0 & 15;
    const int h0 = i0 > j0 ? i0 : j0, l0 = i0 + j0 - h0;
    const int trow0 = h0 * (h0 + 1) / 2 + l0;
    const int i1 = e1 >> 4, j1 = e1 & 15;
    const int h1 = i1 > j1 ? i1 : j1, l1 = i1 + j1 - h1;
    const int trow1 = h1 * (h1 + 1) / 2 + l1;

    float* gout = out + (size_t)p0 * 256;
    #pragma unroll 8
    for (int a = 0; a < 64; ++a) {
        gout[(size_t)a * 256 + e0] = sm.tri[trow0 * 67 + a];
        gout[(size_t)a * 256 + e1] = sm.tri[trow1 * 67 + a];
    }
}

extern "C" void kernel_launch(void* const* d_in, const int* in_sizes, int n_in,
                              void* d_out, int out_size, void* d_ws, size_t ws_size,
                              hipStream_t stream) {
    const float* x = (const float*)d_in[0];
    float* out = (float*)d_out;
    hipLaunchKernelGGL(fused_gram_inv, dim3(1024), dim3(128), 0, stream, x, out);
}